// Round 1
// baseline (1331.603 us; speedup 1.0000x reference)
//
#include <hip/hip_runtime.h>

#define NV   163842
#define NF   327680
#define BB   2
#define INC  64
#define NECK 32
#define OUTC 128
#define NT   (BB*NV)
#define EPSB 1e-5f

// workspace float offsets
#define F_SX   0
#define F_SS   64
#define F_A1   4160
#define F_C1   4192
#define F_ASC  4224
#define F_CSC  4352
#define F_S2S  4480
#define F_S2Q  4512
#define F_A2   4544
#define F_C2   4576
#define F_SHR  4608
#define F_SS2  4640
#define F_A3   5664
#define F_C3   5792
#define STATN  5920
#define F_Y1   6144
#define F_H2   (F_Y1 + NT*NECK)
#define F_I18  (F_H2 + NT*NECK)
#define F_WEW  (F_I18 + NV*18)
#define F_WNS  (F_WEW + NV*18)

// ---------------- x moments: Sx[64], SS[64x64] ----------------
__global__ __launch_bounds__(256) void k_xmoments(const float* __restrict__ x,
                                                  float* __restrict__ ws) {
    __shared__ __align__(16) float xt[64][68];
    const int tid = threadIdx.x;
    const int bi = tid >> 4, bj = tid & 15;
    float acc[4][4];
#pragma unroll
    for (int a = 0; a < 4; ++a)
#pragma unroll
        for (int b = 0; b < 4; ++b) acc[a][b] = 0.f;
    float sx = 0.f;
    const int NTILES = (NT + 63) >> 6;
    for (int t = blockIdx.x; t < NTILES; t += gridDim.x) {
        const int s0 = t << 6;
        __syncthreads();
#pragma unroll
        for (int it = 0; it < 16; ++it) {
            int idx = tid + it * 256;
            int c = idx >> 6, v = idx & 63;
            int s = s0 + v;
            float val = 0.f;
            if (s < NT) {
                int b = (s >= NV) ? 1 : 0;
                int n = s - b * NV;
                val = x[(b * INC + c) * NV + n];
            }
            xt[v][c] = val;
        }
        __syncthreads();
#pragma unroll 4
        for (int v = 0; v < 64; ++v) {
            float4 t1 = *(const float4*)&xt[v][bi * 4];
            float4 t2 = *(const float4*)&xt[v][bj * 4];
            float xi[4] = {t1.x, t1.y, t1.z, t1.w};
            float xj[4] = {t2.x, t2.y, t2.z, t2.w};
#pragma unroll
            for (int a = 0; a < 4; ++a)
#pragma unroll
                for (int b = 0; b < 4; ++b) acc[a][b] += xi[a] * xj[b];
        }
        if (tid < 64) {
            for (int v = 0; v < 64; ++v) sx += xt[v][tid];
        }
    }
    float* SS = ws + F_SS;
#pragma unroll
    for (int a = 0; a < 4; ++a)
#pragma unroll
        for (int b = 0; b < 4; ++b)
            atomicAdd(&SS[(bi * 4 + a) * 64 + bj * 4 + b], acc[a][b]);
    if (tid < 64) atomicAdd(&ws[F_SX + tid], sx);
}

// ---------------- fold1: BN1 + BNsc params from x moments ----------------
__global__ __launch_bounds__(256) void k_fold1(const float* __restrict__ w1,
                                               const float* __restrict__ g1,
                                               const float* __restrict__ be1,
                                               const float* __restrict__ wsc,
                                               const float* __restrict__ gsc,
                                               const float* __restrict__ besc,
                                               float* __restrict__ ws) {
    __shared__ float SSl[4096];
    __shared__ float Sxl[64];
    const int tid = threadIdx.x;
    for (int i = tid; i < 4096; i += 256) SSl[i] = ws[F_SS + i];
    if (tid < 64) Sxl[tid] = ws[F_SX + tid];
    __syncthreads();
    if (tid >= 32) return;
    const int bk = blockIdx.x;
    const float* w;
    float gamma, beta;
    float *pa, *pc;
    if (bk == 0) {
        w = w1 + tid * 64; gamma = g1[tid]; beta = be1[tid];
        pa = ws + F_A1 + tid; pc = ws + F_C1 + tid;
    } else {
        int o = (bk - 1) * 32 + tid;
        w = wsc + o * 64; gamma = gsc[o]; beta = besc[o];
        pa = ws + F_ASC + o; pc = ws + F_CSC + o;
    }
    float4 wr[16];
#pragma unroll
    for (int i = 0; i < 16; ++i) wr[i] = *(const float4*)(w + i * 4);
    float dotm = 0.f, quad = 0.f;
#pragma unroll
    for (int i4 = 0; i4 < 16; ++i4) {
        float4 wi = wr[i4];
        float rd[4] = {0.f, 0.f, 0.f, 0.f};
#pragma unroll
        for (int j4 = 0; j4 < 16; ++j4) {
            float4 wj = wr[j4];
#pragma unroll
            for (int r = 0; r < 4; ++r) {
                const float* row = &SSl[(i4 * 4 + r) * 64 + j4 * 4];
                rd[r] += row[0] * wj.x + row[1] * wj.y + row[2] * wj.z + row[3] * wj.w;
            }
        }
        dotm += wi.x * Sxl[i4 * 4] + wi.y * Sxl[i4 * 4 + 1] + wi.z * Sxl[i4 * 4 + 2] + wi.w * Sxl[i4 * 4 + 3];
        quad += wi.x * rd[0] + wi.y * rd[1] + wi.z * rd[2] + wi.w * rd[3];
    }
    const float invN = 1.0f / (float)NT;
    const float mean0 = dotm * invN;
    const float var = quad * invN - mean0 * mean0;
    const float a = gamma * rsqrtf(var + EPSB);
    *pa = a;
    *pc = beta - a * mean0;
}

// ---------------- conv1 + bn1 + relu -> y1 (B,NV,32) ----------------
__global__ __launch_bounds__(256) void k_conv1(const float* __restrict__ x,
                                               const float* __restrict__ w1,
                                               float* __restrict__ y1,
                                               const float* __restrict__ ws) {
    __shared__ __align__(16) float xt[64][68];
    const int tid = threadIdx.x;
    const int NTILE = (NV + 63) >> 6;  // 2561
    const int b = blockIdx.x / NTILE;
    const int t = blockIdx.x % NTILE;
    const int n0 = t << 6;
    const int c = tid & 31;
    float4 wr[16];
#pragma unroll
    for (int i = 0; i < 16; ++i) wr[i] = *(const float4*)(w1 + c * 64 + i * 4);
    const float a1 = ws[F_A1 + c], c1 = ws[F_C1 + c];
#pragma unroll
    for (int it = 0; it < 16; ++it) {
        int idx = tid + it * 256;
        int cc = idx >> 6, v = idx & 63;
        int n = n0 + v;
        xt[v][cc] = (n < NV) ? x[(b * INC + cc) * NV + n] : 0.f;
    }
    __syncthreads();
    const int vslot = tid >> 5;
#pragma unroll
    for (int vl = 0; vl < 8; ++vl) {
        int v = vslot * 8 + vl;
        float acc = 0.f;
#pragma unroll
        for (int i = 0; i < 16; ++i) {
            float4 xv = *(const float4*)&xt[v][i * 4];
            acc += wr[i].x * xv.x + wr[i].y * xv.y + wr[i].z * xv.z + wr[i].w * xv.w;
        }
        int n = n0 + v;
        if (n < NV) y1[(b * NV + n) * 32 + c] = fmaxf(a1 * acc + c1, 0.f);
    }
}

// ---------------- precompute 18-point gradient stencil ----------------
__global__ __launch_bounds__(256) void k_w18(const int* __restrict__ idx_F2V,
                                             const float* __restrict__ vals_F2V,
                                             const int* __restrict__ idx_G,
                                             const float* __restrict__ vals_G,
                                             const float* __restrict__ EW,
                                             const float* __restrict__ NS,
                                             int* __restrict__ i18,
                                             float* __restrict__ wew,
                                             float* __restrict__ wns) {
    const int n = blockIdx.x * 256 + threadIdx.x;
    if (n >= NV) return;
#pragma unroll
    for (int k = 0; k < 6; ++k) {
        int f = idx_F2V[n * 6 + k];
        float fv = vals_F2V[n * 6 + k];
        float e0 = EW[f * 3], e1 = EW[f * 3 + 1], e2 = EW[f * 3 + 2];
        float s0 = NS[f * 3], s1 = NS[f * 3 + 1], s2 = NS[f * 3 + 2];
#pragma unroll
        for (int j = 0; j < 3; ++j) {
            float g0 = vals_G[f * 9 + j], g1 = vals_G[f * 9 + 3 + j], g2 = vals_G[f * 9 + 6 + j];
            i18[n * 18 + k * 3 + j] = idx_G[f * 3 + j];
            wew[n * 18 + k * 3 + j] = fv * (g0 * e0 + g1 * e1 + g2 * e2);
            wns[n * 18 + k * 3 + j] = fv * (g0 * s0 + g1 * s1 + g2 * s2);
        }
    }
}

// ---------------- meshconv fused: gathers + tap-einsum -> h2, bn2 stats ----------------
__global__ __launch_bounds__(256) void k_meshconv(const float* __restrict__ y1,
                                                  const float* __restrict__ coeffs,
                                                  const int* __restrict__ idx_L,
                                                  const float* __restrict__ vals_L,
                                                  const int* __restrict__ i18,
                                                  const float* __restrict__ w18ew,
                                                  const float* __restrict__ w18ns,
                                                  float* __restrict__ h2,
                                                  float* __restrict__ ws) {
    __shared__ __align__(16) float cf[4096];          // [c][o][k]
    __shared__ __align__(16) float fl[4096];          // [w][g][bh][c][k]
    __shared__ float ssum[32], sssq[32];
    const int tid = threadIdx.x;
    for (int idx = tid; idx < 4096; idx += 256) {
        int o = idx >> 7, r = idx & 127, c = r >> 2, k = r & 3;
        cf[(c * 32 + o) * 4 + k] = coeffs[idx];
    }
    if (tid < 32) { ssum[tid] = 0.f; sssq[tid] = 0.f; }
    __syncthreads();
    const int w = tid >> 6;
    const int lane = tid & 63;
    const int bh = (tid >> 5) & 1;
    const int c = tid & 31;
    float lsum = 0.f, lssq = 0.f;
    const int NCHUNK = (NV + 15) >> 4;
    for (int chunk = blockIdx.x; chunk < NCHUNK; chunk += gridDim.x) {
        const int n0 = (chunk << 4) + (w << 2);
        // ---- phase 1: gather feats for 4 vertices (both batches via half-waves)
#pragma unroll
        for (int g = 0; g < 4; ++g) {
            const int n = n0 + g;
            float4 feat = make_float4(0.f, 0.f, 0.f, 0.f);
            if (n < NV) {
                int il = 0; float vl_ = 0.f;
                if (lane < 7) { il = idx_L[n * 7 + lane]; vl_ = vals_L[n * 7 + lane]; }
                int ig = 0; float we_ = 0.f, wn_ = 0.f;
                if (lane < 18) {
                    ig = i18[n * 18 + lane];
                    we_ = w18ew[n * 18 + lane];
                    wn_ = w18ns[n * 18 + lane];
                }
                const float* yb = y1 + bh * (NV * 32);
                feat.x = yb[n * 32 + c];
                float lap = 0.f, gew = 0.f, gns = 0.f;
#pragma unroll
                for (int j = 0; j < 7; ++j) {
                    int vi = __shfl(il, j);
                    float wv = __shfl(vl_, j);
                    lap += wv * yb[vi * 32 + c];
                }
#pragma unroll
                for (int j = 0; j < 18; ++j) {
                    int vi = __shfl(ig, j);
                    float we = __shfl(we_, j);
                    float wn = __shfl(wn_, j);
                    float val = yb[vi * 32 + c];
                    gew += we * val;
                    gns += wn * val;
                }
                feat.y = lap; feat.z = gew; feat.w = gns;
            }
            *(float4*)&fl[(((w * 4 + g) * 2 + bh) * 32 + c) * 4] = feat;
        }
        // ---- phase 2: einsum over (c,k) -> 32 outputs (same wave, no barrier)
        float acc[4];
#pragma unroll
        for (int g = 0; g < 4; ++g) acc[g] = 0.f;
        const int o = c;
        for (int ci = 0; ci < 32; ++ci) {
            float4 cv = *(const float4*)&cf[(ci * 32 + o) * 4];
#pragma unroll
            for (int g = 0; g < 4; ++g) {
                float4 fv = *(const float4*)&fl[(((w * 4 + g) * 2 + bh) * 32 + ci) * 4];
                acc[g] += cv.x * fv.x + cv.y * fv.y + cv.z * fv.z + cv.w * fv.w;
            }
        }
#pragma unroll
        for (int g = 0; g < 4; ++g) {
            const int n = n0 + g;
            if (n < NV) {
                float v = acc[g];
                h2[(bh * NV + n) * 32 + o] = v;
                lsum += v;
                lssq += v * v;
            }
        }
    }
    atomicAdd(&ssum[c], lsum);
    atomicAdd(&sssq[c], lssq);
    __syncthreads();
    if (tid < 32) {
        atomicAdd(&ws[F_S2S + tid], ssum[tid]);
        atomicAdd(&ws[F_S2Q + tid], sssq[tid]);
    }
}

// ---------------- fold2: BN2 params ----------------
__global__ void k_fold2(const float* __restrict__ g2, const float* __restrict__ be2,
                        float* __restrict__ ws) {
    const int c = threadIdx.x;
    if (c < 32) {
        const float invN = 1.0f / (float)NT;
        float m = ws[F_S2S + c] * invN;
        float var = ws[F_S2Q + c] * invN - m * m;
        float a = g2[c] * rsqrtf(var + EPSB);
        ws[F_A2 + c] = a;
        ws[F_C2 + c] = be2[c] - a * m;
    }
}

// ---------------- hr moments: Shr[32], SS2[32x32] of relu(bn2(h2)) ----------------
__global__ __launch_bounds__(256) void k_hrmoments(const float* __restrict__ h2,
                                                   float* __restrict__ ws) {
    __shared__ __align__(16) float ht[64][36];
    const int tid = threadIdx.x;
    const int cl = tid & 31;
    const float a2 = ws[F_A2 + cl], c2 = ws[F_C2 + cl];
    const int sg = tid >> 6;
    const int t6 = tid & 63;
    const int bi = t6 >> 3, bj = t6 & 7;
    float acc[4][4];
#pragma unroll
    for (int a = 0; a < 4; ++a)
#pragma unroll
        for (int b = 0; b < 4; ++b) acc[a][b] = 0.f;
    float sx = 0.f;
    const int NTILES = (NT + 63) >> 6;
    for (int t = blockIdx.x; t < NTILES; t += gridDim.x) {
        const int s0 = t << 6;
        __syncthreads();
#pragma unroll
        for (int it = 0; it < 8; ++it) {
            int idx = tid + it * 256;
            int v = idx >> 5;
            int s = s0 + v;
            float val = 0.f;
            if (s < NT) val = fmaxf(a2 * h2[s * 32 + cl] + c2, 0.f);
            ht[v][cl] = val;
        }
        __syncthreads();
#pragma unroll 4
        for (int vv = 0; vv < 16; ++vv) {
            int v = sg * 16 + vv;
            float4 t1 = *(const float4*)&ht[v][bi * 4];
            float4 t2 = *(const float4*)&ht[v][bj * 4];
            float xi[4] = {t1.x, t1.y, t1.z, t1.w};
            float xj[4] = {t2.x, t2.y, t2.z, t2.w};
#pragma unroll
            for (int a = 0; a < 4; ++a)
#pragma unroll
                for (int b = 0; b < 4; ++b) acc[a][b] += xi[a] * xj[b];
        }
        if (tid < 32) {
            for (int v = 0; v < 64; ++v) sx += ht[v][tid];
        }
    }
    float* SS2 = ws + F_SS2;
#pragma unroll
    for (int a = 0; a < 4; ++a)
#pragma unroll
        for (int b = 0; b < 4; ++b)
            atomicAdd(&SS2[(bi * 4 + a) * 32 + bj * 4 + b], acc[a][b]);
    if (tid < 32) atomicAdd(&ws[F_SHR + tid], sx);
}

// ---------------- fold3: BN3 params from hr moments ----------------
__global__ __launch_bounds__(128) void k_fold3(const float* __restrict__ w3,
                                               const float* __restrict__ g3,
                                               const float* __restrict__ be3,
                                               float* __restrict__ ws) {
    __shared__ float SSl[1024];
    __shared__ float Sl[32];
    const int tid = threadIdx.x;
    for (int i = tid; i < 1024; i += 128) SSl[i] = ws[F_SS2 + i];
    if (tid < 32) Sl[tid] = ws[F_SHR + tid];
    __syncthreads();
    const int o = tid;
    float4 wr[8];
#pragma unroll
    for (int i = 0; i < 8; ++i) wr[i] = *(const float4*)(w3 + o * 32 + i * 4);
    float dotm = 0.f, quad = 0.f;
#pragma unroll
    for (int i4 = 0; i4 < 8; ++i4) {
        float4 wi = wr[i4];
        float rd[4] = {0.f, 0.f, 0.f, 0.f};
#pragma unroll
        for (int j4 = 0; j4 < 8; ++j4) {
            float4 wj = wr[j4];
#pragma unroll
            for (int r = 0; r < 4; ++r) {
                const float* row = &SSl[(i4 * 4 + r) * 32 + j4 * 4];
                rd[r] += row[0] * wj.x + row[1] * wj.y + row[2] * wj.z + row[3] * wj.w;
            }
        }
        dotm += wi.x * Sl[i4 * 4] + wi.y * Sl[i4 * 4 + 1] + wi.z * Sl[i4 * 4 + 2] + wi.w * Sl[i4 * 4 + 3];
        quad += wi.x * rd[0] + wi.y * rd[1] + wi.z * rd[2] + wi.w * rd[3];
    }
    const float invN = 1.0f / (float)NT;
    const float mean0 = dotm * invN;
    const float var = quad * invN - mean0 * mean0;
    const float a = g3[o] * rsqrtf(var + EPSB);
    ws[F_A3 + o] = a;
    ws[F_C3 + o] = be3[o] - a * mean0;
}

// ---------------- final: conv3+bn3 + shortcut(conv_sc+bn_sc recompute) + relu ----------------
__global__ __launch_bounds__(256) void k_final(const float* __restrict__ x,
                                               const float* __restrict__ h2,
                                               const float* __restrict__ w3,
                                               const float* __restrict__ wsc,
                                               const float* __restrict__ ws,
                                               float* __restrict__ out) {
    __shared__ __align__(16) float xt[32][68];
    __shared__ __align__(16) float ht[32][36];
    __shared__ float ol[128 * 33];
    const int tid = threadIdx.x;
    const int NTILE = (NV + 31) >> 5;  // 5121
    const int b = blockIdx.x / NTILE;
    const int t = blockIdx.x % NTILE;
    const int n0 = t << 5;
    const int rem = NV - n0;
    const int cl = tid & 31;
    const float a2 = ws[F_A2 + cl], c2 = ws[F_C2 + cl];
#pragma unroll
    for (int it = 0; it < 8; ++it) {
        int idx = tid + it * 256;
        int cc = idx >> 5, v = idx & 31;
        xt[v][cc] = (v < rem) ? x[(b * INC + cc) * NV + n0 + v] : 0.f;
    }
#pragma unroll
    for (int it = 0; it < 4; ++it) {
        int idx = tid + it * 256;
        int v = idx >> 5;
        float val = 0.f;
        if (v < rem) val = fmaxf(a2 * h2[(b * NV + n0 + v) * 32 + cl] + c2, 0.f);
        ht[v][cl] = val;
    }
    const int o = tid & 127;
    float4 w3r[8];
    float4 wscr[16];
#pragma unroll
    for (int i = 0; i < 8; ++i) w3r[i] = *(const float4*)(w3 + o * 32 + i * 4);
#pragma unroll
    for (int i = 0; i < 16; ++i) wscr[i] = *(const float4*)(wsc + o * 64 + i * 4);
    const float a3 = ws[F_A3 + o], c3 = ws[F_C3 + o];
    const float asc = ws[F_ASC + o], csc = ws[F_CSC + o];
    __syncthreads();
    const int vslot = tid >> 7;
#pragma unroll
    for (int vl = 0; vl < 16; ++vl) {
        int v = vslot * 16 + vl;
        float acc3 = 0.f, accsc = 0.f;
#pragma unroll
        for (int i = 0; i < 8; ++i) {
            float4 h4 = *(const float4*)&ht[v][i * 4];
            acc3 += w3r[i].x * h4.x + w3r[i].y * h4.y + w3r[i].z * h4.z + w3r[i].w * h4.w;
        }
#pragma unroll
        for (int i = 0; i < 16; ++i) {
            float4 x4 = *(const float4*)&xt[v][i * 4];
            accsc += wscr[i].x * x4.x + wscr[i].y * x4.y + wscr[i].z * x4.z + wscr[i].w * x4.w;
        }
        ol[o * 33 + v] = fmaxf(a3 * acc3 + c3 + asc * accsc + csc, 0.f);
    }
    __syncthreads();
#pragma unroll
    for (int it = 0; it < 16; ++it) {
        int idx = tid + it * 256;
        int oo = idx >> 5, v = idx & 31;
        if (v < rem) out[(b * OUTC + oo) * NV + n0 + v] = ol[oo * 33 + v];
    }
}

extern "C" void kernel_launch(void* const* d_in, const int* in_sizes, int n_in,
                              void* d_out, int out_size, void* d_ws, size_t ws_size,
                              hipStream_t stream) {
    (void)in_sizes; (void)n_in; (void)out_size; (void)ws_size;
    const float* x        = (const float*)d_in[0];
    const float* w1       = (const float*)d_in[1];
    const float* g1       = (const float*)d_in[3];
    const float* be1      = (const float*)d_in[4];
    const float* coeffs   = (const float*)d_in[5];
    const float* g2       = (const float*)d_in[7];
    const float* be2      = (const float*)d_in[8];
    const float* w3       = (const float*)d_in[9];
    const float* g3       = (const float*)d_in[11];
    const float* be3      = (const float*)d_in[12];
    const float* wsc      = (const float*)d_in[13];
    const float* gsc      = (const float*)d_in[15];
    const float* besc     = (const float*)d_in[16];
    const int*   idx_G    = (const int*)d_in[17];
    const float* vals_G   = (const float*)d_in[18];
    const float* EW       = (const float*)d_in[19];
    const float* NS       = (const float*)d_in[20];
    const int*   idx_L    = (const int*)d_in[21];
    const float* vals_L   = (const float*)d_in[22];
    const int*   idx_F2V  = (const int*)d_in[23];
    const float* vals_F2V = (const float*)d_in[24];
    float* ws  = (float*)d_ws;
    float* out = (float*)d_out;

    hipMemsetAsync(ws, 0, STATN * sizeof(float), stream);
    hipLaunchKernelGGL(k_xmoments, dim3(1024), dim3(256), 0, stream, x, ws);
    hipLaunchKernelGGL(k_w18, dim3((NV + 255) / 256), dim3(256), 0, stream,
                       idx_F2V, vals_F2V, idx_G, vals_G, EW, NS,
                       (int*)(ws + F_I18), ws + F_WEW, ws + F_WNS);
    hipLaunchKernelGGL(k_fold1, dim3(5), dim3(256), 0, stream, w1, g1, be1, wsc, gsc, besc, ws);
    hipLaunchKernelGGL(k_conv1, dim3(BB * 2561), dim3(256), 0, stream, x, w1, ws + F_Y1, ws);
    hipLaunchKernelGGL(k_meshconv, dim3(2048), dim3(256), 0, stream,
                       ws + F_Y1, coeffs, idx_L, vals_L,
                       (const int*)(ws + F_I18), ws + F_WEW, ws + F_WNS,
                       ws + F_H2, ws);
    hipLaunchKernelGGL(k_fold2, dim3(1), dim3(32), 0, stream, g2, be2, ws);
    hipLaunchKernelGGL(k_hrmoments, dim3(640), dim3(256), 0, stream, ws + F_H2, ws);
    hipLaunchKernelGGL(k_fold3, dim3(1), dim3(128), 0, stream, w3, g3, be3, ws);
    hipLaunchKernelGGL(k_final, dim3(BB * 5121), dim3(256), 0, stream, x, ws + F_H2, w3, wsc, ws, out);
}

// Round 3
// 1052.344 us; speedup vs baseline: 1.2654x; 1.2654x over previous
//
#include <hip/hip_runtime.h>

#define NV   163842
#define NF   327680
#define BB   2
#define INC  64
#define NECK 32
#define OUTC 128
#define NT   (BB*NV)
#define EPSB 1e-5f

typedef unsigned short ushort_t;
typedef __attribute__((ext_vector_type(8))) short bf16x8;
typedef __attribute__((ext_vector_type(4))) float f32x4;

// workspace float offsets
#define F_SX   0
#define F_SS   64
#define F_A1   4160
#define F_C1   4192
#define F_ASC  4224
#define F_CSC  4352
#define F_S2S  4480
#define F_S2Q  4512
#define F_A2   4544
#define F_C2   4576
#define F_SHR  4608
#define F_SS2  4640
#define F_A3   5664
#define F_C3   5792
#define STATN  5920
#define F_CFB  6144
#define F_Y1   8192
#define F_H2   (F_Y1 + NT*16)
#define F_I18  (F_H2 + NT*16)
#define F_WEW  (F_I18 + NV*18)
#define F_WNS  (F_WEW + NV*18)

// feat row stride in ushorts: 128 data + 8 pad (272B, 16B-aligned, 2-way-bank-safe)
#define FSTR 136

__device__ __forceinline__ float bf2f(ushort_t u) {
    union { unsigned int i; float f; } x; x.i = ((unsigned int)u) << 16; return x.f;
}
__device__ __forceinline__ ushort_t f2bf(float f) {
    union { float f; unsigned int i; } x; x.f = f;
    unsigned int r = x.i + 0x7fffu + ((x.i >> 16) & 1u);
    return (ushort_t)(r >> 16);
}

// ---------------- x moments: Sx[64], SS[64x64] ----------------
__global__ __launch_bounds__(256) void k_xmoments(const float* __restrict__ x,
                                                  float* __restrict__ ws) {
    __shared__ __align__(16) float xt[64][68];
    const int tid = threadIdx.x;
    const int bi = tid >> 4, bj = tid & 15;
    float acc[4][4];
#pragma unroll
    for (int a = 0; a < 4; ++a)
#pragma unroll
        for (int b = 0; b < 4; ++b) acc[a][b] = 0.f;
    float sx = 0.f;
    const int NTILES = (NT + 63) >> 6;
    for (int t = blockIdx.x; t < NTILES; t += gridDim.x) {
        const int s0 = t << 6;
        __syncthreads();
#pragma unroll
        for (int it = 0; it < 16; ++it) {
            int idx = tid + it * 256;
            int c = idx >> 6, v = idx & 63;
            int s = s0 + v;
            float val = 0.f;
            if (s < NT) {
                int b = (s >= NV) ? 1 : 0;
                int n = s - b * NV;
                val = x[(b * INC + c) * NV + n];
            }
            xt[v][c] = val;
        }
        __syncthreads();
#pragma unroll 4
        for (int v = 0; v < 64; ++v) {
            float4 t1 = *(const float4*)&xt[v][bi * 4];
            float4 t2 = *(const float4*)&xt[v][bj * 4];
            float xi[4] = {t1.x, t1.y, t1.z, t1.w};
            float xj[4] = {t2.x, t2.y, t2.z, t2.w};
#pragma unroll
            for (int a = 0; a < 4; ++a)
#pragma unroll
                for (int b = 0; b < 4; ++b) acc[a][b] += xi[a] * xj[b];
        }
        if (tid < 64) {
            for (int v = 0; v < 64; ++v) sx += xt[v][tid];
        }
    }
    float* SS = ws + F_SS;
#pragma unroll
    for (int a = 0; a < 4; ++a)
#pragma unroll
        for (int b = 0; b < 4; ++b)
            atomicAdd(&SS[(bi * 4 + a) * 64 + bj * 4 + b], acc[a][b]);
    if (tid < 64) atomicAdd(&ws[F_SX + tid], sx);
}

// ---------------- fold1: BN1 + BNsc params from x moments ----------------
__global__ __launch_bounds__(256) void k_fold1(const float* __restrict__ w1,
                                               const float* __restrict__ g1,
                                               const float* __restrict__ be1,
                                               const float* __restrict__ wsc,
                                               const float* __restrict__ gsc,
                                               const float* __restrict__ besc,
                                               float* __restrict__ ws) {
    __shared__ float SSl[4096];
    __shared__ float Sxl[64];
    const int tid = threadIdx.x;
    for (int i = tid; i < 4096; i += 256) SSl[i] = ws[F_SS + i];
    if (tid < 64) Sxl[tid] = ws[F_SX + tid];
    __syncthreads();
    if (tid >= 32) return;
    const int bk = blockIdx.x;
    const float* w;
    float gamma, beta;
    float *pa, *pc;
    if (bk == 0) {
        w = w1 + tid * 64; gamma = g1[tid]; beta = be1[tid];
        pa = ws + F_A1 + tid; pc = ws + F_C1 + tid;
    } else {
        int o = (bk - 1) * 32 + tid;
        w = wsc + o * 64; gamma = gsc[o]; beta = besc[o];
        pa = ws + F_ASC + o; pc = ws + F_CSC + o;
    }
    float4 wr[16];
#pragma unroll
    for (int i = 0; i < 16; ++i) wr[i] = *(const float4*)(w + i * 4);
    float dotm = 0.f, quad = 0.f;
#pragma unroll
    for (int i4 = 0; i4 < 16; ++i4) {
        float4 wi = wr[i4];
        float rd[4] = {0.f, 0.f, 0.f, 0.f};
#pragma unroll
        for (int j4 = 0; j4 < 16; ++j4) {
            float4 wj = wr[j4];
#pragma unroll
            for (int r = 0; r < 4; ++r) {
                const float* row = &SSl[(i4 * 4 + r) * 64 + j4 * 4];
                rd[r] += row[0] * wj.x + row[1] * wj.y + row[2] * wj.z + row[3] * wj.w;
            }
        }
        dotm += wi.x * Sxl[i4 * 4] + wi.y * Sxl[i4 * 4 + 1] + wi.z * Sxl[i4 * 4 + 2] + wi.w * Sxl[i4 * 4 + 3];
        quad += wi.x * rd[0] + wi.y * rd[1] + wi.z * rd[2] + wi.w * rd[3];
    }
    const float invN = 1.0f / (float)NT;
    const float mean0 = dotm * invN;
    const float var = quad * invN - mean0 * mean0;
    const float a = gamma * rsqrtf(var + EPSB);
    *pa = a;
    *pc = beta - a * mean0;
}

// ---------------- conv1 + bn1 + relu -> y1 bf16 (B,NV,32) ----------------
__global__ __launch_bounds__(256) void k_conv1(const float* __restrict__ x,
                                               const float* __restrict__ w1,
                                               ushort_t* __restrict__ y1,
                                               const float* __restrict__ ws) {
    __shared__ __align__(16) float xt[64][68];
    const int tid = threadIdx.x;
    const int NTILE = (NV + 63) >> 6;  // 2561
    const int b = blockIdx.x / NTILE;
    const int t = blockIdx.x % NTILE;
    const int n0 = t << 6;
    const int c = tid & 31;
    float4 wr[16];
#pragma unroll
    for (int i = 0; i < 16; ++i) wr[i] = *(const float4*)(w1 + c * 64 + i * 4);
    const float a1 = ws[F_A1 + c], c1 = ws[F_C1 + c];
#pragma unroll
    for (int it = 0; it < 16; ++it) {
        int idx = tid + it * 256;
        int cc = idx >> 6, v = idx & 63;
        int n = n0 + v;
        xt[v][cc] = (n < NV) ? x[(b * INC + cc) * NV + n] : 0.f;
    }
    __syncthreads();
    const int vslot = tid >> 5;
#pragma unroll
    for (int vl = 0; vl < 8; ++vl) {
        int v = vslot * 8 + vl;
        float acc = 0.f;
#pragma unroll
        for (int i = 0; i < 16; ++i) {
            float4 xv = *(const float4*)&xt[v][i * 4];
            acc += wr[i].x * xv.x + wr[i].y * xv.y + wr[i].z * xv.z + wr[i].w * xv.w;
        }
        int n = n0 + v;
        if (n < NV) y1[(b * NV + n) * 32 + c] = f2bf(fmaxf(a1 * acc + c1, 0.f));
    }
}

// ---------------- precompute 18-point gradient stencil ----------------
__global__ __launch_bounds__(256) void k_w18(const int* __restrict__ idx_F2V,
                                             const float* __restrict__ vals_F2V,
                                             const int* __restrict__ idx_G,
                                             const float* __restrict__ vals_G,
                                             const float* __restrict__ EW,
                                             const float* __restrict__ NS,
                                             int* __restrict__ i18,
                                             float* __restrict__ wew,
                                             float* __restrict__ wns) {
    const int n = blockIdx.x * 256 + threadIdx.x;
    if (n >= NV) return;
#pragma unroll
    for (int k = 0; k < 6; ++k) {
        int f = idx_F2V[n * 6 + k];
        float fv = vals_F2V[n * 6 + k];
        float e0 = EW[f * 3], e1 = EW[f * 3 + 1], e2 = EW[f * 3 + 2];
        float s0 = NS[f * 3], s1 = NS[f * 3 + 1], s2 = NS[f * 3 + 2];
#pragma unroll
        for (int j = 0; j < 3; ++j) {
            float g0 = vals_G[f * 9 + j], g1 = vals_G[f * 9 + 3 + j], g2 = vals_G[f * 9 + 6 + j];
            i18[n * 18 + k * 3 + j] = idx_G[f * 3 + j];
            wew[n * 18 + k * 3 + j] = fv * (g0 * e0 + g1 * e1 + g2 * e2);
            wns[n * 18 + k * 3 + j] = fv * (g0 * s0 + g1 * s1 + g2 * s2);
        }
    }
}

// ---------------- coeffs -> bf16 ----------------
__global__ __launch_bounds__(256) void k_cvtcoef(const float* __restrict__ c,
                                                 ushort_t* __restrict__ cb) {
    int i = blockIdx.x * 256 + threadIdx.x;
    if (i < 4096) cb[i] = f2bf(c[i]);
}

// ---------------- meshconv: gathers + MFMA einsum -> h2 bf16, bn2 stats ----------------
// wave-independent: each wave processes chunks of 16 vertices x 2 batches (32 instances)
__global__ __launch_bounds__(256, 3) void k_meshconv(const ushort_t* __restrict__ y1,
                                                     const ushort_t* __restrict__ cfb,
                                                     const int* __restrict__ idx_L,
                                                     const float* __restrict__ vals_L,
                                                     const int* __restrict__ i18,
                                                     const float* __restrict__ w18ew,
                                                     const float* __restrict__ w18ns,
                                                     ushort_t* __restrict__ h2,
                                                     float* __restrict__ ws) {
    // per-wave feat buffer: 32 instances x 128 k (bf16), row stride FSTR=136 ushorts
    __shared__ __align__(16) ushort_t feat[4][32 * FSTR];
    __shared__ float sred[64];
    const int tid = threadIdx.x;
    const int w = __builtin_amdgcn_readfirstlane(tid >> 6);
    const int lane = tid & 63;
    ushort_t* fw = &feat[w][0];
    const int bh = lane >> 5;
    const int c = lane & 31;
    const int ybase = bh * (NV * 32);
    const int o16 = lane & 15;
    const int kg = lane >> 4;  // 0..3

    if (tid < 64) sred[tid] = 0.f;
    __syncthreads();

    float ssum[8], sssq[8];
#pragma unroll
    for (int i = 0; i < 8; ++i) { ssum[i] = 0.f; sssq[i] = 0.f; }

    const int gw = blockIdx.x * 4 + w;
    const int NW = gridDim.x * 4;
    const int NCH = (NV + 15) >> 4;  // 10241

    for (int ch = gw; ch < NCH; ch += NW) {
        const int n0 = ch << 4;
        // ---- gather phase: build feat rows (bf16) for 16 vertices x 2 batches
        for (int g = 0; g < 16; ++g) {
            const int n = n0 + g;                    // wave-uniform
            const bool ok = (n < NV);
            const int nn = ok ? n : (NV - 1);
            float fx = bf2f(y1[ybase + (nn << 5) + c]);
            float lap = 0.f, gew = 0.f, gns = 0.f;
            const int* ilp = idx_L + nn * 7;
            const float* vlp = vals_L + nn * 7;
#pragma unroll
            for (int j = 0; j < 7; ++j) {
                int vi = ilp[j];
                float wv = vlp[j];
                lap += wv * bf2f(y1[ybase + (vi << 5) + c]);
            }
            const int* igp = i18 + nn * 18;
            const float* wep = w18ew + nn * 18;
            const float* wnp = w18ns + nn * 18;
#pragma unroll
            for (int j = 0; j < 18; ++j) {
                int vi = igp[j];
                float we = wep[j], wn = wnp[j];
                float v = bf2f(y1[ybase + (vi << 5) + c]);
                gew += we * v;
                gns += wn * v;
            }
            if (!ok) { fx = 0.f; lap = 0.f; gew = 0.f; gns = 0.f; }
            unsigned int lo = (unsigned int)f2bf(fx) | ((unsigned int)f2bf(lap) << 16);
            unsigned int hi = (unsigned int)f2bf(gew) | ((unsigned int)f2bf(gns) << 16);
            const int inst = bh * 16 + g;
            *(uint2*)(fw + inst * FSTR + (c << 2)) = make_uint2(lo, hi);
        }
        // ---- MFMA phase: D[o=32][inst=32] = coeffs[32x128] * feat[128x32]
        f32x4 acc[2][2];
#pragma unroll
        for (int mt = 0; mt < 2; ++mt)
#pragma unroll
            for (int nt = 0; nt < 2; ++nt) acc[mt][nt] = (f32x4){0.f, 0.f, 0.f, 0.f};
        bf16x8 bfr[2][4];
#pragma unroll
        for (int nt = 0; nt < 2; ++nt)
#pragma unroll
            for (int kt = 0; kt < 4; ++kt)
                bfr[nt][kt] = *(const bf16x8*)(fw + (nt * 16 + o16) * FSTR + kt * 32 + kg * 8);
#pragma unroll
        for (int mt = 0; mt < 2; ++mt) {
#pragma unroll
            for (int kt = 0; kt < 4; ++kt) {
                bf16x8 af = *(const bf16x8*)(cfb + (mt * 16 + o16) * 128 + kt * 32 + kg * 8);
                acc[mt][0] = __builtin_amdgcn_mfma_f32_16x16x32_bf16(af, bfr[0][kt], acc[mt][0], 0, 0, 0);
                acc[mt][1] = __builtin_amdgcn_mfma_f32_16x16x32_bf16(af, bfr[1][kt], acc[mt][1], 0, 0, 0);
            }
        }
        // ---- write h2 (bf16) + accumulate bn2 stats
        const int n = n0 + o16;
        if (n < NV) {
#pragma unroll
            for (int nt = 0; nt < 2; ++nt) {
                const int rowb = ((nt * NV + n) << 5);
#pragma unroll
                for (int mt = 0; mt < 2; ++mt) {
#pragma unroll
                    for (int r = 0; r < 4; ++r) {
                        float v = acc[mt][nt][r];
                        int o = mt * 16 + kg * 4 + r;
                        h2[rowb + o] = f2bf(v);
                        ssum[mt * 4 + r] += v;
                        sssq[mt * 4 + r] += v * v;
                    }
                }
            }
        }
    }

    // ---- stats reduction: sum over the 16 instance-lanes in each group
#pragma unroll
    for (int si = 0; si < 8; ++si) {
#pragma unroll
        for (int m = 1; m < 16; m <<= 1) {
            ssum[si] += __shfl_xor(ssum[si], m, 16);
            sssq[si] += __shfl_xor(sssq[si], m, 16);
        }
    }
    if (o16 == 0) {
#pragma unroll
        for (int mt = 0; mt < 2; ++mt)
#pragma unroll
            for (int r = 0; r < 4; ++r) {
                int o = mt * 16 + kg * 4 + r;
                atomicAdd(&sred[o], ssum[mt * 4 + r]);
                atomicAdd(&sred[32 + o], sssq[mt * 4 + r]);
            }
    }
    __syncthreads();
    if (tid < 64) atomicAdd(&ws[F_S2S + tid], sred[tid]);
}

// ---------------- fold2: BN2 params ----------------
__global__ void k_fold2(const float* __restrict__ g2, const float* __restrict__ be2,
                        float* __restrict__ ws) {
    const int c = threadIdx.x;
    if (c < 32) {
        const float invN = 1.0f / (float)NT;
        float m = ws[F_S2S + c] * invN;
        float var = ws[F_S2Q + c] * invN - m * m;
        float a = g2[c] * rsqrtf(var + EPSB);
        ws[F_A2 + c] = a;
        ws[F_C2 + c] = be2[c] - a * m;
    }
}

// ---------------- hr moments: Shr[32], SS2[32x32] of relu(bn2(h2)) ----------------
__global__ __launch_bounds__(256) void k_hrmoments(const ushort_t* __restrict__ h2,
                                                   float* __restrict__ ws) {
    __shared__ __align__(16) float ht[64][36];
    const int tid = threadIdx.x;
    const int cl = tid & 31;
    const float a2 = ws[F_A2 + cl], c2 = ws[F_C2 + cl];
    const int sg = tid >> 6;
    const int t6 = tid & 63;
    const int bi = t6 >> 3, bj = t6 & 7;
    float acc[4][4];
#pragma unroll
    for (int a = 0; a < 4; ++a)
#pragma unroll
        for (int b = 0; b < 4; ++b) acc[a][b] = 0.f;
    float sx = 0.f;
    const int NTILES = (NT + 63) >> 6;
    for (int t = blockIdx.x; t < NTILES; t += gridDim.x) {
        const int s0 = t << 6;
        __syncthreads();
#pragma unroll
        for (int it = 0; it < 8; ++it) {
            int idx = tid + it * 256;
            int v = idx >> 5;
            int s = s0 + v;
            float val = 0.f;
            if (s < NT) val = fmaxf(a2 * bf2f(h2[s * 32 + cl]) + c2, 0.f);
            ht[v][cl] = val;
        }
        __syncthreads();
#pragma unroll 4
        for (int vv = 0; vv < 16; ++vv) {
            int v = sg * 16 + vv;
            float4 t1 = *(const float4*)&ht[v][bi * 4];
            float4 t2 = *(const float4*)&ht[v][bj * 4];
            float xi[4] = {t1.x, t1.y, t1.z, t1.w};
            float xj[4] = {t2.x, t2.y, t2.z, t2.w};
#pragma unroll
            for (int a = 0; a < 4; ++a)
#pragma unroll
                for (int b = 0; b < 4; ++b) acc[a][b] += xi[a] * xj[b];
        }
        if (tid < 32) {
            for (int v = 0; v < 64; ++v) sx += ht[v][tid];
        }
    }
    float* SS2 = ws + F_SS2;
#pragma unroll
    for (int a = 0; a < 4; ++a)
#pragma unroll
        for (int b = 0; b < 4; ++b)
            atomicAdd(&SS2[(bi * 4 + a) * 32 + bj * 4 + b], acc[a][b]);
    if (tid < 32) atomicAdd(&ws[F_SHR + tid], sx);
}

// ---------------- fold3: BN3 params from hr moments ----------------
__global__ __launch_bounds__(128) void k_fold3(const float* __restrict__ w3,
                                               const float* __restrict__ g3,
                                               const float* __restrict__ be3,
                                               float* __restrict__ ws) {
    __shared__ float SSl[1024];
    __shared__ float Sl[32];
    const int tid = threadIdx.x;
    for (int i = tid; i < 1024; i += 128) SSl[i] = ws[F_SS2 + i];
    if (tid < 32) Sl[tid] = ws[F_SHR + tid];
    __syncthreads();
    const int o = tid;
    float4 wr[8];
#pragma unroll
    for (int i = 0; i < 8; ++i) wr[i] = *(const float4*)(w3 + o * 32 + i * 4);
    float dotm = 0.f, quad = 0.f;
#pragma unroll
    for (int i4 = 0; i4 < 8; ++i4) {
        float4 wi = wr[i4];
        float rd[4] = {0.f, 0.f, 0.f, 0.f};
#pragma unroll
        for (int j4 = 0; j4 < 8; ++j4) {
            float4 wj = wr[j4];
#pragma unroll
            for (int r = 0; r < 4; ++r) {
                const float* row = &SSl[(i4 * 4 + r) * 32 + j4 * 4];
                rd[r] += row[0] * wj.x + row[1] * wj.y + row[2] * wj.z + row[3] * wj.w;
            }
        }
        dotm += wi.x * Sl[i4 * 4] + wi.y * Sl[i4 * 4 + 1] + wi.z * Sl[i4 * 4 + 2] + wi.w * Sl[i4 * 4 + 3];
        quad += wi.x * rd[0] + wi.y * rd[1] + wi.z * rd[2] + wi.w * rd[3];
    }
    const float invN = 1.0f / (float)NT;
    const float mean0 = dotm * invN;
    const float var = quad * invN - mean0 * mean0;
    const float a = g3[o] * rsqrtf(var + EPSB);
    ws[F_A3 + o] = a;
    ws[F_C3 + o] = be3[o] - a * mean0;
}

// ---------------- final: conv3+bn3 + shortcut(conv_sc+bn_sc recompute) + relu ----------------
__global__ __launch_bounds__(256) void k_final(const float* __restrict__ x,
                                               const ushort_t* __restrict__ h2,
                                               const float* __restrict__ w3,
                                               const float* __restrict__ wsc,
                                               const float* __restrict__ ws,
                                               float* __restrict__ out) {
    __shared__ __align__(16) float xt[32][68];
    __shared__ __align__(16) float ht[32][36];
    __shared__ float ol[128 * 33];
    const int tid = threadIdx.x;
    const int NTILE = (NV + 31) >> 5;  // 5121
    const int b = blockIdx.x / NTILE;
    const int t = blockIdx.x % NTILE;
    const int n0 = t << 5;
    const int rem = NV - n0;
    const int cl = tid & 31;
    const float a2 = ws[F_A2 + cl], c2 = ws[F_C2 + cl];
#pragma unroll
    for (int it = 0; it < 8; ++it) {
        int idx = tid + it * 256;
        int cc = idx >> 5, v = idx & 31;
        xt[v][cc] = (v < rem) ? x[(b * INC + cc) * NV + n0 + v] : 0.f;
    }
#pragma unroll
    for (int it = 0; it < 4; ++it) {
        int idx = tid + it * 256;
        int v = idx >> 5;
        float val = 0.f;
        if (v < rem) val = fmaxf(a2 * bf2f(h2[(b * NV + n0 + v) * 32 + cl]) + c2, 0.f);
        ht[v][cl] = val;
    }
    const int o = tid & 127;
    float4 w3r[8];
    float4 wscr[16];
#pragma unroll
    for (int i = 0; i < 8; ++i) w3r[i] = *(const float4*)(w3 + o * 32 + i * 4);
#pragma unroll
    for (int i = 0; i < 16; ++i) wscr[i] = *(const float4*)(wsc + o * 64 + i * 4);
    const float a3 = ws[F_A3 + o], c3 = ws[F_C3 + o];
    const float asc = ws[F_ASC + o], csc = ws[F_CSC + o];
    __syncthreads();
    const int vslot = tid >> 7;
#pragma unroll
    for (int vl = 0; vl < 16; ++vl) {
        int v = vslot * 16 + vl;
        float acc3 = 0.f, accsc = 0.f;
#pragma unroll
        for (int i = 0; i < 8; ++i) {
            float4 h4 = *(const float4*)&ht[v][i * 4];
            acc3 += w3r[i].x * h4.x + w3r[i].y * h4.y + w3r[i].z * h4.z + w3r[i].w * h4.w;
        }
#pragma unroll
        for (int i = 0; i < 16; ++i) {
            float4 x4 = *(const float4*)&xt[v][i * 4];
            accsc += wscr[i].x * x4.x + wscr[i].y * x4.y + wscr[i].z * x4.z + wscr[i].w * x4.w;
        }
        ol[o * 33 + v] = fmaxf(a3 * acc3 + c3 + asc * accsc + csc, 0.f);
    }
    __syncthreads();
#pragma unroll
    for (int it = 0; it < 16; ++it) {
        int idx = tid + it * 256;
        int oo = idx >> 5, v = idx & 31;
        if (v < rem) out[(b * OUTC + oo) * NV + n0 + v] = ol[oo * 33 + v];
    }
}

extern "C" void kernel_launch(void* const* d_in, const int* in_sizes, int n_in,
                              void* d_out, int out_size, void* d_ws, size_t ws_size,
                              hipStream_t stream) {
    (void)in_sizes; (void)n_in; (void)out_size; (void)ws_size;
    const float* x        = (const float*)d_in[0];
    const float* w1       = (const float*)d_in[1];
    const float* g1       = (const float*)d_in[3];
    const float* be1      = (const float*)d_in[4];
    const float* coeffs   = (const float*)d_in[5];
    const float* g2       = (const float*)d_in[7];
    const float* be2      = (const float*)d_in[8];
    const float* w3       = (const float*)d_in[9];
    const float* g3       = (const float*)d_in[11];
    const float* be3      = (const float*)d_in[12];
    const float* wsc      = (const float*)d_in[13];
    const float* gsc      = (const float*)d_in[15];
    const float* besc     = (const float*)d_in[16];
    const int*   idx_G    = (const int*)d_in[17];
    const float* vals_G   = (const float*)d_in[18];
    const float* EW       = (const float*)d_in[19];
    const float* NS       = (const float*)d_in[20];
    const int*   idx_L    = (const int*)d_in[21];
    const float* vals_L   = (const float*)d_in[22];
    const int*   idx_F2V  = (const int*)d_in[23];
    const float* vals_F2V = (const float*)d_in[24];
    float* ws  = (float*)d_ws;
    float* out = (float*)d_out;

    ushort_t* cfb = (ushort_t*)(ws + F_CFB);
    ushort_t* y1  = (ushort_t*)(ws + F_Y1);
    ushort_t* h2  = (ushort_t*)(ws + F_H2);

    hipMemsetAsync(ws, 0, STATN * sizeof(float), stream);
    hipLaunchKernelGGL(k_xmoments, dim3(1024), dim3(256), 0, stream, x, ws);
    hipLaunchKernelGGL(k_w18, dim3((NV + 255) / 256), dim3(256), 0, stream,
                       idx_F2V, vals_F2V, idx_G, vals_G, EW, NS,
                       (int*)(ws + F_I18), ws + F_WEW, ws + F_WNS);
    hipLaunchKernelGGL(k_cvtcoef, dim3(16), dim3(256), 0, stream, coeffs, cfb);
    hipLaunchKernelGGL(k_fold1, dim3(5), dim3(256), 0, stream, w1, g1, be1, wsc, gsc, besc, ws);
    hipLaunchKernelGGL(k_conv1, dim3(BB * 2561), dim3(256), 0, stream, x, w1, y1, ws);
    hipLaunchKernelGGL(k_meshconv, dim3(768), dim3(256), 0, stream,
                       y1, cfb, idx_L, vals_L,
                       (const int*)(ws + F_I18), ws + F_WEW, ws + F_WNS,
                       h2, ws);
    hipLaunchKernelGGL(k_fold2, dim3(1), dim3(32), 0, stream, g2, be2, ws);
    hipLaunchKernelGGL(k_hrmoments, dim3(640), dim3(256), 0, stream, h2, ws);
    hipLaunchKernelGGL(k_fold3, dim3(1), dim3(128), 0, stream, w3, g3, be3, ws);
    hipLaunchKernelGGL(k_final, dim3(BB * 5121), dim3(256), 0, stream, x, h2, w3, wsc, ws, out);
}

// Round 4
// 673.314 us; speedup vs baseline: 1.9777x; 1.5629x over previous
//
#include <hip/hip_runtime.h>

#define NV   163842
#define NF   327680
#define BB   2
#define INC  64
#define NECK 32
#define OUTC 128
#define NT   (BB*NV)
#define EPSB 1e-5f

typedef unsigned short ushort_t;
typedef __attribute__((ext_vector_type(8))) short bf16x8;
typedef __attribute__((ext_vector_type(4))) float f32x4;

// workspace float offsets
#define F_SX   0
#define F_SS   64
#define F_A1   4160
#define F_C1   4192
#define F_ASC  4224
#define F_CSC  4352
#define F_S2S  4480
#define F_S2Q  4512
#define F_A2   4544
#define F_C2   4576
#define F_SHR  4608
#define F_SS2  4640
#define F_A3   5664
#define F_C3   5792
#define STATN  5920
#define F_CF   5920
#define F_CFB  6144
#define F_Y1   8192
#define F_H2   (F_Y1 + NT*16)
#define F_I18  (F_H2 + NT*16)
#define F_WEW  (F_I18 + NV*18)
#define F_WNS  (F_WEW + NV*18)
// wfb (128x96 bf16) aliases the start of y1 — y1 is dead after k_meshconv,
// and k_fold3 (writer) runs strictly after it.

#define FSTR 136

__device__ __forceinline__ float bf2f(ushort_t u) {
    union { unsigned int i; float f; } x; x.i = ((unsigned int)u) << 16; return x.f;
}
__device__ __forceinline__ ushort_t f2bf(float f) {
    union { float f; unsigned int i; } x; x.f = f;
    unsigned int r = x.i + 0x7fffu + ((x.i >> 16) & 1u);
    return (ushort_t)(r >> 16);
}

// ---------------- x moments: Sx[64], SS[64x64] ----------------
__global__ __launch_bounds__(256) void k_xmoments(const float* __restrict__ x,
                                                  float* __restrict__ ws) {
    __shared__ __align__(16) float xt[64][68];
    const int tid = threadIdx.x;
    const int bi = tid >> 4, bj = tid & 15;
    float acc[4][4];
#pragma unroll
    for (int a = 0; a < 4; ++a)
#pragma unroll
        for (int b = 0; b < 4; ++b) acc[a][b] = 0.f;
    float sx = 0.f;
    const int NTILES = (NT + 63) >> 6;
    for (int t = blockIdx.x; t < NTILES; t += gridDim.x) {
        const int s0 = t << 6;
        __syncthreads();
#pragma unroll
        for (int it = 0; it < 16; ++it) {
            int idx = tid + it * 256;
            int c = idx >> 6, v = idx & 63;
            int s = s0 + v;
            float val = 0.f;
            if (s < NT) {
                int b = (s >= NV) ? 1 : 0;
                int n = s - b * NV;
                val = x[(b * INC + c) * NV + n];
            }
            xt[v][c] = val;
        }
        __syncthreads();
#pragma unroll 4
        for (int v = 0; v < 64; ++v) {
            float4 t1 = *(const float4*)&xt[v][bi * 4];
            float4 t2 = *(const float4*)&xt[v][bj * 4];
            float xi[4] = {t1.x, t1.y, t1.z, t1.w};
            float xj[4] = {t2.x, t2.y, t2.z, t2.w};
#pragma unroll
            for (int a = 0; a < 4; ++a)
#pragma unroll
                for (int b = 0; b < 4; ++b) acc[a][b] += xi[a] * xj[b];
        }
        if (tid < 64) {
            for (int v = 0; v < 64; ++v) sx += xt[v][tid];
        }
    }
    float* SS = ws + F_SS;
#pragma unroll
    for (int a = 0; a < 4; ++a)
#pragma unroll
        for (int b = 0; b < 4; ++b)
            atomicAdd(&SS[(bi * 4 + a) * 64 + bj * 4 + b], acc[a][b]);
    if (tid < 64) atomicAdd(&ws[F_SX + tid], sx);
}

// ---------------- fold1: BN1 + BNsc params from x moments ----------------
__global__ __launch_bounds__(256) void k_fold1(const float* __restrict__ w1,
                                               const float* __restrict__ g1,
                                               const float* __restrict__ be1,
                                               const float* __restrict__ wsc,
                                               const float* __restrict__ gsc,
                                               const float* __restrict__ besc,
                                               float* __restrict__ ws) {
    __shared__ float SSl[4096];
    __shared__ float Sxl[64];
    const int tid = threadIdx.x;
    for (int i = tid; i < 4096; i += 256) SSl[i] = ws[F_SS + i];
    if (tid < 64) Sxl[tid] = ws[F_SX + tid];
    __syncthreads();
    if (tid >= 32) return;
    const int bk = blockIdx.x;
    const float* w;
    float gamma, beta;
    float *pa, *pc;
    if (bk == 0) {
        w = w1 + tid * 64; gamma = g1[tid]; beta = be1[tid];
        pa = ws + F_A1 + tid; pc = ws + F_C1 + tid;
    } else {
        int o = (bk - 1) * 32 + tid;
        w = wsc + o * 64; gamma = gsc[o]; beta = besc[o];
        pa = ws + F_ASC + o; pc = ws + F_CSC + o;
    }
    float4 wr[16];
#pragma unroll
    for (int i = 0; i < 16; ++i) wr[i] = *(const float4*)(w + i * 4);
    float dotm = 0.f, quad = 0.f;
#pragma unroll
    for (int i4 = 0; i4 < 16; ++i4) {
        float4 wi = wr[i4];
        float rd[4] = {0.f, 0.f, 0.f, 0.f};
#pragma unroll
        for (int j4 = 0; j4 < 16; ++j4) {
            float4 wj = wr[j4];
#pragma unroll
            for (int r = 0; r < 4; ++r) {
                const float* row = &SSl[(i4 * 4 + r) * 64 + j4 * 4];
                rd[r] += row[0] * wj.x + row[1] * wj.y + row[2] * wj.z + row[3] * wj.w;
            }
        }
        dotm += wi.x * Sxl[i4 * 4] + wi.y * Sxl[i4 * 4 + 1] + wi.z * Sxl[i4 * 4 + 2] + wi.w * Sxl[i4 * 4 + 3];
        quad += wi.x * rd[0] + wi.y * rd[1] + wi.z * rd[2] + wi.w * rd[3];
    }
    const float invN = 1.0f / (float)NT;
    const float mean0 = dotm * invN;
    const float var = quad * invN - mean0 * mean0;
    const float a = gamma * rsqrtf(var + EPSB);
    *pa = a;
    *pc = beta - a * mean0;
}

// ---------------- conv1 + bn1 + relu -> y1 bf16 (B,NV,32) ----------------
__global__ __launch_bounds__(256) void k_conv1(const float* __restrict__ x,
                                               const float* __restrict__ w1,
                                               ushort_t* __restrict__ y1,
                                               const float* __restrict__ ws) {
    __shared__ __align__(16) float xt[64][68];
    const int tid = threadIdx.x;
    const int NTILE = (NV + 63) >> 6;  // 2561
    const int b = blockIdx.x / NTILE;
    const int t = blockIdx.x % NTILE;
    const int n0 = t << 6;
    const int c = tid & 31;
    float4 wr[16];
#pragma unroll
    for (int i = 0; i < 16; ++i) wr[i] = *(const float4*)(w1 + c * 64 + i * 4);
    const float a1 = ws[F_A1 + c], c1 = ws[F_C1 + c];
#pragma unroll
    for (int it = 0; it < 16; ++it) {
        int idx = tid + it * 256;
        int cc = idx >> 6, v = idx & 63;
        int n = n0 + v;
        xt[v][cc] = (n < NV) ? x[(b * INC + cc) * NV + n] : 0.f;
    }
    __syncthreads();
    const int vslot = tid >> 5;
#pragma unroll
    for (int vl = 0; vl < 8; ++vl) {
        int v = vslot * 8 + vl;
        float acc = 0.f;
#pragma unroll
        for (int i = 0; i < 16; ++i) {
            float4 xv = *(const float4*)&xt[v][i * 4];
            acc += wr[i].x * xv.x + wr[i].y * xv.y + wr[i].z * xv.z + wr[i].w * xv.w;
        }
        int n = n0 + v;
        if (n < NV) y1[(b * NV + n) * 32 + c] = f2bf(fmaxf(a1 * acc + c1, 0.f));
    }
}

// ---------------- precompute 18-point gradient stencil ----------------
__global__ __launch_bounds__(256) void k_w18(const int* __restrict__ idx_F2V,
                                             const float* __restrict__ vals_F2V,
                                             const int* __restrict__ idx_G,
                                             const float* __restrict__ vals_G,
                                             const float* __restrict__ EW,
                                             const float* __restrict__ NS,
                                             int* __restrict__ i18,
                                             float* __restrict__ wew,
                                             float* __restrict__ wns) {
    const int n = blockIdx.x * 256 + threadIdx.x;
    if (n >= NV) return;
#pragma unroll
    for (int k = 0; k < 6; ++k) {
        int f = idx_F2V[n * 6 + k];
        float fv = vals_F2V[n * 6 + k];
        float e0 = EW[f * 3], e1 = EW[f * 3 + 1], e2 = EW[f * 3 + 2];
        float s0 = NS[f * 3], s1 = NS[f * 3 + 1], s2 = NS[f * 3 + 2];
#pragma unroll
        for (int j = 0; j < 3; ++j) {
            float g0 = vals_G[f * 9 + j], g1 = vals_G[f * 9 + 3 + j], g2 = vals_G[f * 9 + 6 + j];
            i18[n * 18 + k * 3 + j] = idx_G[f * 3 + j];
            wew[n * 18 + k * 3 + j] = fv * (g0 * e0 + g1 * e1 + g2 * e2);
            wns[n * 18 + k * 3 + j] = fv * (g0 * s0 + g1 * s1 + g2 * s2);
        }
    }
}

// ---------------- coeffs -> bf16 ----------------
__global__ __launch_bounds__(256) void k_cvtcoef(const float* __restrict__ c,
                                                 ushort_t* __restrict__ cb) {
    int i = blockIdx.x * 256 + threadIdx.x;
    if (i < 4096) cb[i] = f2bf(c[i]);
}

// ---------------- meshconv: gathers + MFMA einsum -> h2 bf16, bn2 stats ----------------
__global__ __launch_bounds__(256, 3) void k_meshconv(const ushort_t* __restrict__ y1,
                                                     const ushort_t* __restrict__ cfb,
                                                     const int* __restrict__ idx_L,
                                                     const float* __restrict__ vals_L,
                                                     const int* __restrict__ i18,
                                                     const float* __restrict__ w18ew,
                                                     const float* __restrict__ w18ns,
                                                     ushort_t* __restrict__ h2,
                                                     float* __restrict__ ws) {
    __shared__ __align__(16) ushort_t feat[4][32 * FSTR];
    __shared__ float sred[64];
    const int tid = threadIdx.x;
    const int w = __builtin_amdgcn_readfirstlane(tid >> 6);
    const int lane = tid & 63;
    ushort_t* fw = &feat[w][0];
    const int bh = lane >> 5;
    const int c = lane & 31;
    const int ybase = bh * (NV * 32);
    const int o16 = lane & 15;
    const int kg = lane >> 4;  // 0..3

    if (tid < 64) sred[tid] = 0.f;
    __syncthreads();

    float ssum[8], sssq[8];
#pragma unroll
    for (int i = 0; i < 8; ++i) { ssum[i] = 0.f; sssq[i] = 0.f; }

    const int gw = blockIdx.x * 4 + w;
    const int NW = gridDim.x * 4;
    const int NCH = (NV + 15) >> 4;  // 10241

    for (int ch = gw; ch < NCH; ch += NW) {
        const int n0 = ch << 4;
        for (int g = 0; g < 16; ++g) {
            const int n = n0 + g;
            const bool ok = (n < NV);
            const int nn = ok ? n : (NV - 1);
            float fx = bf2f(y1[ybase + (nn << 5) + c]);
            float lap = 0.f, gew = 0.f, gns = 0.f;
            const int* ilp = idx_L + nn * 7;
            const float* vlp = vals_L + nn * 7;
#pragma unroll
            for (int j = 0; j < 7; ++j) {
                int vi = ilp[j];
                float wv = vlp[j];
                lap += wv * bf2f(y1[ybase + (vi << 5) + c]);
            }
            const int* igp = i18 + nn * 18;
            const float* wep = w18ew + nn * 18;
            const float* wnp = w18ns + nn * 18;
#pragma unroll
            for (int j = 0; j < 18; ++j) {
                int vi = igp[j];
                float we = wep[j], wn = wnp[j];
                float v = bf2f(y1[ybase + (vi << 5) + c]);
                gew += we * v;
                gns += wn * v;
            }
            if (!ok) { fx = 0.f; lap = 0.f; gew = 0.f; gns = 0.f; }
            unsigned int lo = (unsigned int)f2bf(fx) | ((unsigned int)f2bf(lap) << 16);
            unsigned int hi = (unsigned int)f2bf(gew) | ((unsigned int)f2bf(gns) << 16);
            const int inst = bh * 16 + g;
            *(uint2*)(fw + inst * FSTR + (c << 2)) = make_uint2(lo, hi);
        }
        f32x4 acc[2][2];
#pragma unroll
        for (int mt = 0; mt < 2; ++mt)
#pragma unroll
            for (int nt = 0; nt < 2; ++nt) acc[mt][nt] = (f32x4){0.f, 0.f, 0.f, 0.f};
        bf16x8 bfr[2][4];
#pragma unroll
        for (int nt = 0; nt < 2; ++nt)
#pragma unroll
            for (int kt = 0; kt < 4; ++kt)
                bfr[nt][kt] = *(const bf16x8*)(fw + (nt * 16 + o16) * FSTR + kt * 32 + kg * 8);
#pragma unroll
        for (int mt = 0; mt < 2; ++mt) {
#pragma unroll
            for (int kt = 0; kt < 4; ++kt) {
                bf16x8 af = *(const bf16x8*)(cfb + (mt * 16 + o16) * 128 + kt * 32 + kg * 8);
                acc[mt][0] = __builtin_amdgcn_mfma_f32_16x16x32_bf16(af, bfr[0][kt], acc[mt][0], 0, 0, 0);
                acc[mt][1] = __builtin_amdgcn_mfma_f32_16x16x32_bf16(af, bfr[1][kt], acc[mt][1], 0, 0, 0);
            }
        }
        const int n = n0 + o16;
        if (n < NV) {
#pragma unroll
            for (int nt = 0; nt < 2; ++nt) {
                const int rowb = ((nt * NV + n) << 5);
#pragma unroll
                for (int mt = 0; mt < 2; ++mt) {
#pragma unroll
                    for (int r = 0; r < 4; ++r) {
                        float v = acc[mt][nt][r];
                        int o = mt * 16 + kg * 4 + r;
                        h2[rowb + o] = f2bf(v);
                        ssum[mt * 4 + r] += v;
                        sssq[mt * 4 + r] += v * v;
                    }
                }
            }
        }
    }

#pragma unroll
    for (int si = 0; si < 8; ++si) {
#pragma unroll
        for (int m = 1; m < 16; m <<= 1) {
            ssum[si] += __shfl_xor(ssum[si], m, 16);
            sssq[si] += __shfl_xor(sssq[si], m, 16);
        }
    }
    if (o16 == 0) {
#pragma unroll
        for (int mt = 0; mt < 2; ++mt)
#pragma unroll
            for (int r = 0; r < 4; ++r) {
                int o = mt * 16 + kg * 4 + r;
                atomicAdd(&sred[o], ssum[mt * 4 + r]);
                atomicAdd(&sred[32 + o], sssq[mt * 4 + r]);
            }
    }
    __syncthreads();
    if (tid < 64) atomicAdd(&ws[F_S2S + tid], sred[tid]);
}

// ---------------- fold2: BN2 params ----------------
__global__ void k_fold2(const float* __restrict__ g2, const float* __restrict__ be2,
                        float* __restrict__ ws) {
    const int c = threadIdx.x;
    if (c < 32) {
        const float invN = 1.0f / (float)NT;
        float m = ws[F_S2S + c] * invN;
        float var = ws[F_S2Q + c] * invN - m * m;
        float a = g2[c] * rsqrtf(var + EPSB);
        ws[F_A2 + c] = a;
        ws[F_C2 + c] = be2[c] - a * m;
    }
}

// ---------------- hr moments via MFMA SYRK: Shr[32], SS2[32x32] ----------------
__global__ __launch_bounds__(256) void k_hrmoments(const ushort_t* __restrict__ h2,
                                                   float* __restrict__ ws) {
    // per-wave hr^T tile [32 ch][40 verts-stride] bf16 (80B rows, 16B aligned)
    __shared__ __align__(16) ushort_t tile[4][32 * 40];
    __shared__ float red[1056];
    const int tid = threadIdx.x;
    const int w = tid >> 6, l = tid & 63;
    ushort_t* T = &tile[w][0];
    const int c8 = (l & 3) * 8;
    const int v0 = l >> 2;            // 0..15
    const int fr = l & 15, kg = l >> 4;

    for (int i = tid; i < 1056; i += 256) red[i] = 0.f;
    __syncthreads();

    float a2r[8], c2r[8];
#pragma unroll
    for (int j = 0; j < 8; ++j) { a2r[j] = ws[F_A2 + c8 + j]; c2r[j] = ws[F_C2 + c8 + j]; }

    f32x4 acc[2][2];
#pragma unroll
    for (int a = 0; a < 2; ++a)
#pragma unroll
        for (int b = 0; b < 2; ++b) acc[a][b] = (f32x4){0.f, 0.f, 0.f, 0.f};
    float ssum[8];
#pragma unroll
    for (int j = 0; j < 8; ++j) ssum[j] = 0.f;

    const int NCH = (NT + 31) >> 5;  // 10241
    for (int ch = blockIdx.x * 4 + w; ch < NCH; ch += gridDim.x * 4) {
        const int s0 = ch << 5;
#pragma unroll
        for (int i = 0; i < 2; ++i) {
            const int vert = i * 16 + v0;
            const int s = s0 + vert;
            uint4 q = make_uint4(0u, 0u, 0u, 0u);
            const bool ok = (s < NT);
            if (ok) q = *(const uint4*)(h2 + (size_t)s * 32 + c8);
            const ushort_t* qs = (const ushort_t*)&q;
            ushort_t hb[8];
#pragma unroll
            for (int j = 0; j < 8; ++j) {
                float hv = ok ? fmaxf(a2r[j] * bf2f(qs[j]) + c2r[j], 0.f) : 0.f;
                ssum[j] += hv;
                hb[j] = f2bf(hv);
            }
#pragma unroll
            for (int j = 0; j < 8; ++j) T[(c8 + j) * 40 + vert] = hb[j];
        }
        // same-wave LDS write->read (no barrier needed; compiler inserts lgkmcnt)
        bf16x8 f0 = *(const bf16x8*)(T + fr * 40 + kg * 8);
        bf16x8 f1 = *(const bf16x8*)(T + (16 + fr) * 40 + kg * 8);
        acc[0][0] = __builtin_amdgcn_mfma_f32_16x16x32_bf16(f0, f0, acc[0][0], 0, 0, 0);
        acc[0][1] = __builtin_amdgcn_mfma_f32_16x16x32_bf16(f0, f1, acc[0][1], 0, 0, 0);
        acc[1][0] = __builtin_amdgcn_mfma_f32_16x16x32_bf16(f1, f0, acc[1][0], 0, 0, 0);
        acc[1][1] = __builtin_amdgcn_mfma_f32_16x16x32_bf16(f1, f1, acc[1][1], 0, 0, 0);
    }
#pragma unroll
    for (int mt = 0; mt < 2; ++mt)
#pragma unroll
        for (int nt = 0; nt < 2; ++nt)
#pragma unroll
            for (int r = 0; r < 4; ++r)
                atomicAdd(&red[(mt * 16 + kg * 4 + r) * 32 + nt * 16 + fr], acc[mt][nt][r]);
#pragma unroll
    for (int j = 0; j < 8; ++j) {
        float s = ssum[j];
        s += __shfl_xor(s, 4); s += __shfl_xor(s, 8);
        s += __shfl_xor(s, 16); s += __shfl_xor(s, 32);
        if (v0 == 0) atomicAdd(&red[1024 + c8 + j], s);
    }
    __syncthreads();
    for (int i = tid; i < 1024; i += 256) atomicAdd(&ws[F_SS2 + i], red[i]);
    if (tid < 32) atomicAdd(&ws[F_SHR + tid], red[1024 + tid]);
}

// ---------------- fold3: BN3 params + fused final weights Wf (bf16) ----------------
__global__ __launch_bounds__(128) void k_fold3(const float* __restrict__ w3,
                                               const float* __restrict__ wsc,
                                               const float* __restrict__ g3,
                                               const float* __restrict__ be3,
                                               float* __restrict__ ws,
                                               ushort_t* __restrict__ wfb) {
    __shared__ float SSl[1024];
    __shared__ float Sl[32];
    const int tid = threadIdx.x;
    for (int i = tid; i < 1024; i += 128) SSl[i] = ws[F_SS2 + i];
    if (tid < 32) Sl[tid] = ws[F_SHR + tid];
    __syncthreads();
    const int o = tid;
    float4 wr[8];
#pragma unroll
    for (int i = 0; i < 8; ++i) wr[i] = *(const float4*)(w3 + o * 32 + i * 4);
    float dotm = 0.f, quad = 0.f;
#pragma unroll
    for (int i4 = 0; i4 < 8; ++i4) {
        float4 wi = wr[i4];
        float rd[4] = {0.f, 0.f, 0.f, 0.f};
#pragma unroll
        for (int j4 = 0; j4 < 8; ++j4) {
            float4 wj = wr[j4];
#pragma unroll
            for (int r = 0; r < 4; ++r) {
                const float* row = &SSl[(i4 * 4 + r) * 32 + j4 * 4];
                rd[r] += row[0] * wj.x + row[1] * wj.y + row[2] * wj.z + row[3] * wj.w;
            }
        }
        dotm += wi.x * Sl[i4 * 4] + wi.y * Sl[i4 * 4 + 1] + wi.z * Sl[i4 * 4 + 2] + wi.w * Sl[i4 * 4 + 3];
        quad += wi.x * rd[0] + wi.y * rd[1] + wi.z * rd[2] + wi.w * rd[3];
    }
    const float invN = 1.0f / (float)NT;
    const float mean0 = dotm * invN;
    const float var = quad * invN - mean0 * mean0;
    const float a = g3[o] * rsqrtf(var + EPSB);
    const float cbias = be3[o] - a * mean0;
    ws[F_A3 + o] = a;
    ws[F_C3 + o] = cbias;
    const float asc = ws[F_ASC + o], csc = ws[F_CSC + o];
    ws[F_CF + o] = cbias + csc;
#pragma unroll
    for (int i4 = 0; i4 < 8; ++i4) {
        wfb[o * 96 + i4 * 4 + 0] = f2bf(a * wr[i4].x);
        wfb[o * 96 + i4 * 4 + 1] = f2bf(a * wr[i4].y);
        wfb[o * 96 + i4 * 4 + 2] = f2bf(a * wr[i4].z);
        wfb[o * 96 + i4 * 4 + 3] = f2bf(a * wr[i4].w);
    }
    for (int j = 0; j < 64; ++j)
        wfb[o * 96 + 32 + j] = f2bf(asc * wsc[o * 64 + j]);
}

// ---------------- final: fused [conv3+bn3 | conv_sc+bn_sc] MFMA GEMM + relu ----------------
__global__ __launch_bounds__(256) void k_final(const float* __restrict__ x,
                                               const ushort_t* __restrict__ h2,
                                               const ushort_t* __restrict__ wfb,
                                               const float* __restrict__ ws,
                                               float* __restrict__ out) {
    __shared__ __align__(16) ushort_t feat[32 * 104];  // [vert][96+8pad] bf16
    __shared__ __align__(16) float ol[128][33];
    const int tid = threadIdx.x;
    const int w = tid >> 6, l = tid & 63;
    const int fr = l & 15, kg = l >> 4;

    // A-frags: Wf rows w*32 + mt*16 + fr
    bf16x8 af[2][3];
#pragma unroll
    for (int mt = 0; mt < 2; ++mt)
#pragma unroll
        for (int kt = 0; kt < 3; ++kt)
            af[mt][kt] = *(const bf16x8*)(wfb + (w * 32 + mt * 16 + fr) * 96 + kt * 32 + kg * 8);
    float cfr[2][4];
#pragma unroll
    for (int mt = 0; mt < 2; ++mt)
#pragma unroll
        for (int r = 0; r < 4; ++r)
            cfr[mt][r] = ws[F_CF + w * 32 + mt * 16 + kg * 4 + r];

    // feat-build roles
    const int hv = tid >> 3, hc4 = (tid & 7) * 4;
    float a2r[4], c2r[4];
#pragma unroll
    for (int j = 0; j < 4; ++j) { a2r[j] = ws[F_A2 + hc4 + j]; c2r[j] = ws[F_C2 + hc4 + j]; }
    const int xc = tid & 63, xq = tid >> 6;
    // out-write role
    const int oo = tid >> 1, ohalf = tid & 1;

    const int NCHK = (NV + 31) >> 5;  // 5121
    for (int cid = blockIdx.x; cid < 2 * NCHK; cid += gridDim.x) {
        const int b = (cid >= NCHK) ? 1 : 0;
        const int t = cid - b * NCHK;
        const int n0 = t << 5;
        const int rem = NV - n0 < 32 ? NV - n0 : 32;
        // ---- build feat: hr part (32 ch with bn2+relu)
        {
            const int s = b * NV + n0 + hv;
            const bool ok = (hv < rem);
            uint2 q = make_uint2(0u, 0u);
            if (ok) q = *(const uint2*)(h2 + (size_t)s * 32 + hc4);
            const ushort_t* qs = (const ushort_t*)&q;
            unsigned int p0 = 0u, p1 = 0u;
            if (ok) {
                float h0 = fmaxf(a2r[0] * bf2f(qs[0]) + c2r[0], 0.f);
                float h1 = fmaxf(a2r[1] * bf2f(qs[1]) + c2r[1], 0.f);
                float h2v = fmaxf(a2r[2] * bf2f(qs[2]) + c2r[2], 0.f);
                float h3 = fmaxf(a2r[3] * bf2f(qs[3]) + c2r[3], 0.f);
                p0 = (unsigned int)f2bf(h0) | ((unsigned int)f2bf(h1) << 16);
                p1 = (unsigned int)f2bf(h2v) | ((unsigned int)f2bf(h3) << 16);
            }
            *(uint2*)(feat + hv * 104 + hc4) = make_uint2(p0, p1);
        }
        // ---- build feat: x part (64 raw channels)
        {
            const float* xp = x + (size_t)(b * 64 + xc) * NV + n0 + xq * 8;
            float xv[8];
            if (n0 + xq * 8 + 8 <= NV) {
#pragma unroll
                for (int j2 = 0; j2 < 4; ++j2) {
                    float2 t2 = *(const float2*)(xp + j2 * 2);
                    xv[2 * j2] = t2.x; xv[2 * j2 + 1] = t2.y;
                }
            } else {
#pragma unroll
                for (int j = 0; j < 8; ++j)
                    xv[j] = (n0 + xq * 8 + j < NV) ? xp[j] : 0.f;
            }
#pragma unroll
            for (int j = 0; j < 8; ++j)
                feat[(xq * 8 + j) * 104 + 32 + xc] = f2bf(xv[j]);
        }
        __syncthreads();
        // ---- MFMA: 128 out x 32 verts, K=96
        bf16x8 bf[2][3];
#pragma unroll
        for (int nt = 0; nt < 2; ++nt)
#pragma unroll
            for (int kt = 0; kt < 3; ++kt)
                bf[nt][kt] = *(const bf16x8*)(feat + (nt * 16 + fr) * 104 + kt * 32 + kg * 8);
        f32x4 acc[2][2];
#pragma unroll
        for (int mt = 0; mt < 2; ++mt)
#pragma unroll
            for (int nt = 0; nt < 2; ++nt) acc[mt][nt] = (f32x4){0.f, 0.f, 0.f, 0.f};
#pragma unroll
        for (int mt = 0; mt < 2; ++mt)
#pragma unroll
            for (int nt = 0; nt < 2; ++nt)
#pragma unroll
                for (int kt = 0; kt < 3; ++kt)
                    acc[mt][nt] = __builtin_amdgcn_mfma_f32_16x16x32_bf16(af[mt][kt], bf[nt][kt], acc[mt][nt], 0, 0, 0);
#pragma unroll
        for (int mt = 0; mt < 2; ++mt)
#pragma unroll
            for (int nt = 0; nt < 2; ++nt)
#pragma unroll
                for (int r = 0; r < 4; ++r)
                    ol[w * 32 + mt * 16 + kg * 4 + r][nt * 16 + fr] =
                        fmaxf(acc[mt][nt][r] + cfr[mt][r], 0.f);
        __syncthreads();
        // ---- write out (coalesced-ish, 64B segments per row)
        {
            float* po = out + (size_t)(b * 128 + oo) * NV + n0 + ohalf * 16;
            if (rem == 32) {
#pragma unroll
                for (int j2 = 0; j2 < 8; ++j2)
                    *(float2*)(po + j2 * 2) = make_float2(ol[oo][ohalf * 16 + j2 * 2],
                                                         ol[oo][ohalf * 16 + j2 * 2 + 1]);
            } else {
#pragma unroll
                for (int j = 0; j < 16; ++j) {
                    int v = ohalf * 16 + j;
                    if (v < rem) po[j] = ol[oo][v];
                }
            }
        }
        __syncthreads();
    }
}

extern "C" void kernel_launch(void* const* d_in, const int* in_sizes, int n_in,
                              void* d_out, int out_size, void* d_ws, size_t ws_size,
                              hipStream_t stream) {
    (void)in_sizes; (void)n_in; (void)out_size; (void)ws_size;
    const float* x        = (const float*)d_in[0];
    const float* w1       = (const float*)d_in[1];
    const float* g1       = (const float*)d_in[3];
    const float* be1      = (const float*)d_in[4];
    const float* coeffs   = (const float*)d_in[5];
    const float* g2       = (const float*)d_in[7];
    const float* be2      = (const float*)d_in[8];
    const float* w3       = (const float*)d_in[9];
    const float* g3       = (const float*)d_in[11];
    const float* be3      = (const float*)d_in[12];
    const float* wsc      = (const float*)d_in[13];
    const float* gsc      = (const float*)d_in[15];
    const float* besc     = (const float*)d_in[16];
    const int*   idx_G    = (const int*)d_in[17];
    const float* vals_G   = (const float*)d_in[18];
    const float* EW       = (const float*)d_in[19];
    const float* NS       = (const float*)d_in[20];
    const int*   idx_L    = (const int*)d_in[21];
    const float* vals_L   = (const float*)d_in[22];
    const int*   idx_F2V  = (const int*)d_in[23];
    const float* vals_F2V = (const float*)d_in[24];
    float* ws  = (float*)d_ws;
    float* out = (float*)d_out;

    ushort_t* cfb = (ushort_t*)(ws + F_CFB);
    ushort_t* y1  = (ushort_t*)(ws + F_Y1);
    ushort_t* h2  = (ushort_t*)(ws + F_H2);
    ushort_t* wfb = (ushort_t*)(ws + F_Y1);  // aliases y1 (dead after meshconv)

    hipMemsetAsync(ws, 0, STATN * sizeof(float), stream);
    hipLaunchKernelGGL(k_xmoments, dim3(1024), dim3(256), 0, stream, x, ws);
    hipLaunchKernelGGL(k_w18, dim3((NV + 255) / 256), dim3(256), 0, stream,
                       idx_F2V, vals_F2V, idx_G, vals_G, EW, NS,
                       (int*)(ws + F_I18), ws + F_WEW, ws + F_WNS);
    hipLaunchKernelGGL(k_cvtcoef, dim3(16), dim3(256), 0, stream, coeffs, cfb);
    hipLaunchKernelGGL(k_fold1, dim3(5), dim3(256), 0, stream, w1, g1, be1, wsc, gsc, besc, ws);
    hipLaunchKernelGGL(k_conv1, dim3(BB * 2561), dim3(256), 0, stream, x, w1, y1, ws);
    hipLaunchKernelGGL(k_meshconv, dim3(768), dim3(256), 0, stream,
                       y1, cfb, idx_L, vals_L,
                       (const int*)(ws + F_I18), ws + F_WEW, ws + F_WNS,
                       h2, ws);
    hipLaunchKernelGGL(k_fold2, dim3(1), dim3(32), 0, stream, g2, be2, ws);
    hipLaunchKernelGGL(k_hrmoments, dim3(1024), dim3(256), 0, stream, h2, ws);
    hipLaunchKernelGGL(k_fold3, dim3(1), dim3(128), 0, stream, w3, wsc, g3, be3, ws, wfb);
    hipLaunchKernelGGL(k_final, dim3(2048), dim3(256), 0, stream, x, h2, wfb, ws, out);
}